// Round 6
// baseline (801.365 us; speedup 1.0000x reference)
//
#include <hip/hip_runtime.h>

#define T_SEQ 512
#define HID 64
#define NIN 20
#define OUT_N 5

typedef float f32x4 __attribute__((ext_vector_type(4)));
typedef int v4i __attribute__((ext_vector_type(4)));

// D = A*B + D, A from AGPR (keeps weights out of the arch-VGPR budget).
#define MFMA(acc, A, B) \
  asm("v_mfma_f32_16x16x32_bf16 %0, %1, %2, %0" : "+v"(acc) : "a"(A), "v"(B))

// Raw barrier: drain LDS (write visibility) but leave global prefetch in flight.
// sched_barrier(0) fences stop the compiler migrating register-only work
// (MFMA / pointwise VALU) across the phase boundary, which would destroy the
// P1/P2 overlap.
#define BARRIER()                              \
  do {                                         \
    __builtin_amdgcn_sched_barrier(0);         \
    asm volatile("s_waitcnt lgkmcnt(0)\n\ts_barrier" ::: "memory"); \
    __builtin_amdgcn_sched_barrier(0);         \
  } while (0)

// Weight-register overlay (A-waves use 24 slots, B-waves 32).
#define WA_X(g, hl) wr[2 * (g) + (hl)]
#define WA_H(g, kt, hl) wr[8 + 4 * (g) + 2 * (kt) + (hl)]
#define WB_Y(g, kt, hl) wr[4 * (g) + 2 * (kt) + (hl)]
#define WB_H(g, kt, hl) wr[16 + 4 * (g) + 2 * (kt) + (hl)]

// HW packed f32->bf16 conversion (gfx950; no builtin -- inline asm).
__device__ __forceinline__ unsigned cvt_pk_bf16(float a, float b) {
  unsigned r;
  asm("v_cvt_pk_bf16_f32 %0, %1, %2" : "=v"(r) : "v"(a), "v"(b));
  return r;  // low16 = bf16(a), high16 = bf16(b)
}
// hi/lo pair split: hw = packed bf16(a,b); lw = packed bf16 of exact residuals.
__device__ __forceinline__ void split_pair(float a, float b, unsigned &hw, unsigned &lw) {
  hw = cvt_pk_bf16(a, b);
  const float ah = __uint_as_float(hw << 16);
  const float bh = __uint_as_float(hw & 0xffff0000u);
  lw = cvt_pk_bf16(a - ah, b - bh);
}
__device__ __forceinline__ void pack_frags(const float* v, v4i &hi, v4i &lo) {
#pragma unroll
  for (int d = 0; d < 4; ++d) {
    unsigned hw, lw;
    split_pair(v[2 * d], v[2 * d + 1], hw, lw);
    hi[d] = (int)hw;
    lo[d] = (int)lw;
  }
}

// lane L <- lane L^8, on the VALU pipe (DPP row_ror:8; (l+8)%16 == l^8).
__device__ __forceinline__ float xor8(float v) {
  return __int_as_float(
      __builtin_amdgcn_mov_dpp(__float_as_int(v), 0x128, 0xf, 0xf, true));
}

__device__ __forceinline__ float sigm(float v) { return __builtin_amdgcn_rcpf(1.f + __expf(-v)); }
__device__ __forceinline__ float ftanh(float v) {
  float a = fabsf(v), e = __expf(-2.f * a);
  return copysignf((1.f - e) * __builtin_amdgcn_rcpf(1.f + e), v);
}

// Split pointwise: lanes n16<8 do D-rows r=0,1; lanes n16>=8 take r=2,3 of the
// partner (DPP xor8) for batch nb=lane&7. Bias is in the acc init.
__device__ __forceinline__ void pointwise(const f32x4* acc, int grp, float &ca, float &cb,
                                          unsigned &hpk, unsigned &lpk) {
  float s[4][2];
#pragma unroll
  for (int g = 0; g < 4; ++g) {
    const float z = xor8(acc[g][2]);
    const float w2 = xor8(acc[g][3]);
    s[g][0] = grp ? z : acc[g][0];
    s[g][1] = grp ? w2 : acc[g][1];
  }
  float hv0, hv1;
#pragma unroll
  for (int v = 0; v < 2; ++v) {
    const float iv = sigm(s[0][v]), fv = sigm(s[1][v]);
    const float gv = ftanh(s[2][v]), ov = sigm(s[3][v]);
    float &c = v ? cb : ca;
    c = fv * c + iv * gv;
    const float h = ov * ftanh(c);
    (v ? hv1 : hv0) = h;
  }
  split_pair(hv0, hv1, hpk, lpk);
}

// Layer-pipelined fused LSTM, PHASE-SPLIT: 8 waves/block, 256 blocks.
// Round-robin wave placement puts one A-wave + one B-wave per SIMD; two
// barriers per step arrange that each phase has one group issuing MFMAs while
// the other runs its pointwise tail (MFMA/VALU co-schedule, m114):
//   P1: A-MFMA(i)               | B-pointwise(i-2) -> write h1(i-2)@par
//   P2: A-pointwise(i)->h0(i)@par | B-MFMA(i-1): reads h0(i-1)@par^1, h1(i-2)@par
// Hazards: every write->read pair crosses >=1 barrier; rings by parity.
// h-exchange LDS: [layer][parity][hi|lo][row=batch16][word=pair32], word idx
// XOR-swizzled by (row&7)<<2 -> B-frag = 1 aligned ds_read_b128/plane, 0 conflicts.
__global__ __launch_bounds__(512, 2) void lstm_pipe(
    const float* __restrict__ x,
    const float* __restrict__ w_ih0, const float* __restrict__ w_hh0,
    const float* __restrict__ b_ih0, const float* __restrict__ b_hh0,
    const float* __restrict__ w_ih1, const float* __restrict__ w_hh1,
    const float* __restrict__ b_ih1, const float* __restrict__ b_hh1,
    const float* __restrict__ w_out, const float* __restrict__ b_out,
    float* __restrict__ out) {
  __shared__ __align__(16) unsigned hpf[4096];  // 16 KiB

  const int tid = threadIdx.x;
  const int lane = tid & 63;
  const int wv = __builtin_amdgcn_readfirstlane(tid >> 6);  // 0..7
  const int isB = wv >> 2;   // 0 = layer0 group, 1 = layer1 group
  const int w = wv & 3;      // unit group [16w, 16w+16)
  const int q = lane >> 4;
  const int n16 = lane & 15;
  const int nb = lane & 7;
  const int grp = (lane >> 3) & 1;
  const int blk = blockIdx.x;

  for (int e = tid; e < 4096; e += 512) hpf[e] = 0u;

  // reader: word offsets within a row for kt=0 / kt=1 (swizzle-folded)
  const int sw4 = (n16 & 7) << 2;
  const int b0w = (4 * q) ^ sw4;       // kt=0
  const int b1w = b0w ^ 16;            // kt=1
  // writer: this lane owns units (u0, u0+1) for batch nb -> pair u0>>1
  const int u0 = 16 * w + 4 * q + 2 * grp;
  const int wroff = (isB ? 2048 : 0) + nb * 32 + ((u0 >> 1) ^ (nb << 2));

  // ---- weights -> AGPR overlay (bf16 hi/lo pack). ----
  v4i wr[32];
  f32x4 biasf[4];
  {
    float vv[8];
    if (!isB) {
#pragma unroll
      for (int g = 0; g < 4; ++g) {
        const int row = g * HID + 16 * w + n16;
#pragma unroll
        for (int j = 0; j < 8; ++j) {
          const int k = 8 * q + j;
          vv[j] = (k < NIN) ? w_ih0[row * NIN + k] : 0.f;
        }
        pack_frags(vv, WA_X(g, 0), WA_X(g, 1));
#pragma unroll
        for (int kt = 0; kt < 2; ++kt) {
#pragma unroll
          for (int j = 0; j < 8; ++j) vv[j] = w_hh0[row * HID + 32 * kt + 8 * q + j];
          pack_frags(vv, WA_H(g, kt, 0), WA_H(g, kt, 1));
        }
#pragma unroll
        for (int r = 0; r < 4; ++r) {
          const int br = g * HID + 16 * w + 4 * q + r;
          biasf[g][r] = b_ih0[br] + b_hh0[br];
        }
      }
    } else {
#pragma unroll
      for (int g = 0; g < 4; ++g) {
        const int row = g * HID + 16 * w + n16;
#pragma unroll
        for (int kt = 0; kt < 2; ++kt) {
#pragma unroll
          for (int j = 0; j < 8; ++j) vv[j] = w_ih1[row * HID + 32 * kt + 8 * q + j];
          pack_frags(vv, WB_Y(g, kt, 0), WB_Y(g, kt, 1));
#pragma unroll
          for (int j = 0; j < 8; ++j) vv[j] = w_hh1[row * HID + 32 * kt + 8 * q + j];
          pack_frags(vv, WB_H(g, kt, 0), WB_H(g, kt, 1));
        }
#pragma unroll
        for (int r = 0; r < 4; ++r) {
          const int br = g * HID + 16 * w + 4 * q + r;
          biasf[g][r] = b_ih1[br] + b_hh1[br];
        }
      }
    }
  }

  // ---- x streaming (A-waves): two contiguous dwordx4 per step (k = 8q..8q+7) ----
  const float* xp0 = x;
  const float* xp1 = x;
  int st0 = 0, st1 = 0;
  v4i xmask = {0, 0, 0, 0};
  f32x4 xva = {0.f, 0.f, 0.f, 0.f}, xvb = {0.f, 0.f, 0.f, 0.f};
  float ca = 0.f, cb = 0.f;
  if (!isB) {
    const int k0 = 8 * q;
    const bool v0 = (k0 + 3 < NIN);  // q <= 2
    const bool v1 = (k0 + 7 < NIN);  // q <= 1
    const float* xb = x + (size_t)(blk * 8 + nb) * T_SEQ * NIN;
    xp0 = v0 ? xb + k0 : x;          // invalid lanes park on x[0] (in-bounds, masked)
    xp1 = v1 ? xb + k0 + 4 : x;
    st0 = v0 ? NIN : 0;
    st1 = v1 ? NIN : 0;
#pragma unroll
    for (int d = 0; d < 4; ++d) {
      const unsigned m0 = (k0 + 2 * d < NIN) ? 0x0000ffffu : 0u;
      const unsigned m1 = (k0 + 2 * d + 1 < NIN) ? 0xffff0000u : 0u;
      xmask[d] = (int)(m0 | m1);
    }
    xva = *(const f32x4*)xp0;
    xvb = *(const f32x4*)xp1;
    xp0 += st0;
    xp1 += st1;
  }

  __syncthreads();  // LDS zero-init visible

  // Single acc serves both roles (ranges disjoint: A P1->P2, B P2->next P1).
  f32x4 acc[4];

#pragma unroll 1
  for (int i = 0; i <= T_SEQ + 1; ++i) {
    const int par = i & 1;

    // ================= Phase 1 =================
    if (!isB) {
      if (i < T_SEQ) {
        // A-MFMA for layer 0, time i: acc = b + Wx.x(i) + Wh.h0(i-1)
        const unsigned* r0 = hpf + (par ^ 1) * 1024 + n16 * 32;
        v4i hh0 = *(const v4i*)(r0 + b0w);
        v4i hl0 = *(const v4i*)(r0 + 512 + b0w);
        v4i hh1 = *(const v4i*)(r0 + b1w);
        v4i hl1 = *(const v4i*)(r0 + 512 + b1w);
        const bool pf = i < T_SEQ - 1;
        f32x4 xna = xva, xnb2 = xvb;
        if (pf) {  // prefetch x(i+1); stays in flight across barriers
          xna = *(const f32x4*)xp0;
          xnb2 = *(const f32x4*)xp1;
          xp0 += st0;
          xp1 += st1;
        }
        float xv[8];
#pragma unroll
        for (int d = 0; d < 4; ++d) { xv[d] = xva[d]; xv[4 + d] = xvb[d]; }
        v4i xhi, xlo;
        pack_frags(xv, xhi, xlo);
#pragma unroll
        for (int d = 0; d < 4; ++d) { xhi[d] &= xmask[d]; xlo[d] &= xmask[d]; }
#pragma unroll
        for (int g = 0; g < 4; ++g) acc[g] = biasf[g];
#pragma unroll
        for (int g = 0; g < 4; ++g) {
          MFMA(acc[g], WA_X(g, 0), xhi);
          MFMA(acc[g], WA_X(g, 0), xlo);
          MFMA(acc[g], WA_X(g, 1), xhi);
        }
#pragma unroll
        for (int g = 0; g < 4; ++g) {
          MFMA(acc[g], WA_H(g, 0, 0), hh0);
          MFMA(acc[g], WA_H(g, 0, 0), hl0);
          MFMA(acc[g], WA_H(g, 0, 1), hh0);
        }
#pragma unroll
        for (int g = 0; g < 4; ++g) {
          MFMA(acc[g], WA_H(g, 1, 0), hh1);
          MFMA(acc[g], WA_H(g, 1, 0), hl1);
          MFMA(acc[g], WA_H(g, 1, 1), hh1);
        }
        xva = xna;
        xvb = xnb2;
      }
    } else {
      if (i >= 2) {
        // B-pointwise for layer 1, time i-2 (acc from previous iteration's P2)
        unsigned hpk, lpk;
        pointwise(acc, grp, ca, cb, hpk, lpk);
        hpf[wroff + par * 1024] = hpk;        // h1(i-2) @ parity (i-2)&1 == par
        hpf[wroff + par * 1024 + 512] = lpk;
      }
    }
    BARRIER();

    // ================= Phase 2 =================
    if (!isB) {
      if (i < T_SEQ) {
        // A-pointwise for layer 0, time i -> h0(i)
        unsigned hpk, lpk;
        pointwise(acc, grp, ca, cb, hpk, lpk);
        hpf[wroff + par * 1024] = hpk;
        hpf[wroff + par * 1024 + 512] = lpk;
      }
    } else {
      if (i >= 1 && i <= T_SEQ) {
        // B-MFMA for layer 1, time i-1: acc = b + Wy.h0(i-1) + Wh.h1(i-2)
        const unsigned* r0 = hpf + (par ^ 1) * 1024 + n16 * 32;         // y = h0(i-1)
        const unsigned* r1 = hpf + 2048 + par * 1024 + n16 * 32;        // h1(i-2)
        v4i yh0 = *(const v4i*)(r0 + b0w);
        v4i yl0 = *(const v4i*)(r0 + 512 + b0w);
        v4i yh1 = *(const v4i*)(r0 + b1w);
        v4i yl1 = *(const v4i*)(r0 + 512 + b1w);
        v4i hh0 = *(const v4i*)(r1 + b0w);
        v4i hl0 = *(const v4i*)(r1 + 512 + b0w);
        v4i hh1 = *(const v4i*)(r1 + b1w);
        v4i hl1 = *(const v4i*)(r1 + 512 + b1w);
#pragma unroll
        for (int g = 0; g < 4; ++g) acc[g] = biasf[g];
#pragma unroll
        for (int g = 0; g < 4; ++g) {
          MFMA(acc[g], WB_Y(g, 0, 0), yh0);
          MFMA(acc[g], WB_Y(g, 0, 0), yl0);
          MFMA(acc[g], WB_Y(g, 0, 1), yh0);
        }
#pragma unroll
        for (int g = 0; g < 4; ++g) {
          MFMA(acc[g], WB_H(g, 0, 0), hh0);
          MFMA(acc[g], WB_H(g, 0, 0), hl0);
          MFMA(acc[g], WB_H(g, 0, 1), hh0);
        }
#pragma unroll
        for (int g = 0; g < 4; ++g) {
          MFMA(acc[g], WB_Y(g, 1, 0), yh1);
          MFMA(acc[g], WB_Y(g, 1, 0), yl1);
          MFMA(acc[g], WB_Y(g, 1, 1), yh1);
        }
#pragma unroll
        for (int g = 0; g < 4; ++g) {
          MFMA(acc[g], WB_H(g, 1, 0), hh1);
          MFMA(acc[g], WB_H(g, 1, 0), hl1);
          MFMA(acc[g], WB_H(g, 1, 1), hh1);
        }
      }
    }
    BARRIER();
  }

  // ---- projection: out[b] = h1(511) @ w_out^T + b_out.
  // h1(511) written at i = T_SEQ+1 (P1), parity (T_SEQ+1)&1 = 1. ----
  if (tid < 8 * OUT_N) {
    const int b = tid / OUT_N, j = tid - b * OUT_N;
    float s = b_out[j];
    const unsigned* hrow = hpf + 2048 + 1024 + b * 32;  // layer1, parity 1, hi plane
    const int swb = b << 2;                             // b < 8
    for (int p = 0; p < 32; ++p) {
      const int wsw = p ^ swb;
      const unsigned hw = hrow[wsw];
      const unsigned lw = hrow[wsw + 512];
      const float h0v = __uint_as_float(hw << 16) + __uint_as_float(lw << 16);
      const float h1v = __uint_as_float(hw & 0xffff0000u) + __uint_as_float(lw & 0xffff0000u);
      s = fmaf(w_out[j * HID + 2 * p], h0v, s);
      s = fmaf(w_out[j * HID + 2 * p + 1], h1v, s);
    }
    out[(blk * 8 + b) * OUT_N + j] = s;
  }
}

extern "C" void kernel_launch(void* const* d_in, const int* in_sizes, int n_in,
                              void* d_out, int out_size, void* d_ws, size_t ws_size,
                              hipStream_t stream) {
  const float* x = (const float*)d_in[0];
  const float* w_ih0 = (const float*)d_in[1];
  const float* w_hh0 = (const float*)d_in[2];
  const float* b_ih0 = (const float*)d_in[3];
  const float* b_hh0 = (const float*)d_in[4];
  const float* w_ih1 = (const float*)d_in[5];
  const float* w_hh1 = (const float*)d_in[6];
  const float* b_ih1 = (const float*)d_in[7];
  const float* b_hh1 = (const float*)d_in[8];
  const float* w_out = (const float*)d_in[9];
  const float* b_out = (const float*)d_in[10];
  float* out = (float*)d_out;

  hipLaunchKernelGGL(lstm_pipe, dim3(2048 / 8), dim3(512), 0, stream,
                     x, w_ih0, w_hh0, b_ih0, b_hh0,
                     w_ih1, w_hh1, b_ih1, b_hh1, w_out, b_out, out);
}

// Round 7
// 677.608 us; speedup vs baseline: 1.1826x; 1.1826x over previous
//
#include <hip/hip_runtime.h>

#define T_SEQ 512
#define HID 64
#define NIN 20
#define OUT_N 5

typedef float f32x4 __attribute__((ext_vector_type(4)));
typedef int v4i __attribute__((ext_vector_type(4)));

#if __has_builtin(__builtin_amdgcn_exp2f)
#define EXP2(x) __builtin_amdgcn_exp2f(x)
#else
#define EXP2(x) exp2f(x)
#endif

#define LG2E 1.44269504088896340736f

// D = A*B + D, A from AGPR (keeps weights out of the arch-VGPR budget).
#define MFMA(acc, A, B) \
  asm("v_mfma_f32_16x16x32_bf16 %0, %1, %2, %0" : "+v"(acc) : "a"(A), "v"(B))

// Raw barrier: drain LDS (write visibility) but leave global prefetch in flight
// (avoids __syncthreads' vmcnt(0) drain). No sched_barrier fences: the HW
// scheduler's free drift between the A/B waves IS the overlap (r6 lesson).
#define BAR() asm volatile("s_waitcnt lgkmcnt(0)\n\ts_barrier" ::: "memory")

// Weight-register overlay (A-waves use 24 slots, B-waves 32).
#define WA_X(g, hl) wr[2 * (g) + (hl)]
#define WA_H(g, kt, hl) wr[8 + 4 * (g) + 2 * (kt) + (hl)]
#define WB_Y(g, kt, hl) wr[4 * (g) + 2 * (kt) + (hl)]
#define WB_H(g, kt, hl) wr[16 + 4 * (g) + 2 * (kt) + (hl)]

// HW packed f32->bf16 conversion (gfx950; no builtin -- inline asm).
__device__ __forceinline__ unsigned cvt_pk_bf16(float a, float b) {
  unsigned r;
  asm("v_cvt_pk_bf16_f32 %0, %1, %2" : "=v"(r) : "v"(a), "v"(b));
  return r;  // low16 = bf16(a), high16 = bf16(b)
}
// hi/lo pair split: hw = packed bf16(a,b); lw = packed bf16 of exact residuals.
__device__ __forceinline__ void split_pair(float a, float b, unsigned &hw, unsigned &lw) {
  hw = cvt_pk_bf16(a, b);
  const float ah = __uint_as_float(hw << 16);
  const float bh = __uint_as_float(hw & 0xffff0000u);
  lw = cvt_pk_bf16(a - ah, b - bh);
}
__device__ __forceinline__ void pack_frags(const float* v, v4i &hi, v4i &lo) {
#pragma unroll
  for (int d = 0; d < 4; ++d) {
    unsigned hw, lw;
    split_pair(v[2 * d], v[2 * d + 1], hw, lw);
    hi[d] = (int)hw;
    lo[d] = (int)lw;
  }
}
// Pack the two x dwordx4 halves directly into masked MFMA fragments.
__device__ __forceinline__ void pack_x(const f32x4 &a, const f32x4 &b, const v4i &m,
                                       v4i &hi, v4i &lo) {
  unsigned hw, lw;
  split_pair(a[0], a[1], hw, lw); hi[0] = (int)(hw & m[0]); lo[0] = (int)(lw & m[0]);
  split_pair(a[2], a[3], hw, lw); hi[1] = (int)(hw & m[1]); lo[1] = (int)(lw & m[1]);
  split_pair(b[0], b[1], hw, lw); hi[2] = (int)(hw & m[2]); lo[2] = (int)(lw & m[2]);
  split_pair(b[2], b[3], hw, lw); hi[3] = (int)(hw & m[3]); lo[3] = (int)(lw & m[3]);
}

// lane L <- lane L^8, on the VALU pipe (DPP row_ror:8; (l+8)%16 == l^8).
__device__ __forceinline__ float xor8(float v) {
  return __int_as_float(
      __builtin_amdgcn_mov_dpp(__float_as_int(v), 0x128, 0xf, 0xf, true));
}

// Gates arrive pre-scaled: sigmoid gates by log2(e), tanh gate by 2*log2(e),
// so EXP2 is a bare v_exp_f32 (no ln2 multiply, shorter serial chain).
__device__ __forceinline__ float sigm2(float v) {  // v = log2(e) * gate
  return __builtin_amdgcn_rcpf(1.f + EXP2(-v));
}
__device__ __forceinline__ float tanh2(float v) {  // v = 2*log2(e) * arg
  float a = fabsf(v), e = EXP2(-a);
  return copysignf((1.f - e) * __builtin_amdgcn_rcpf(1.f + e), v);
}

// Split pointwise: lanes n16<8 do D-rows r=0,1; lanes n16>=8 take r=2,3 of the
// partner (DPP xor8) for batch nb=lane&7. Bias (pre-scaled) is in the acc init.
__device__ __forceinline__ void pointwise(const f32x4* acc, int grp, float &ca, float &cb,
                                          unsigned &hpk, unsigned &lpk) {
  float s[4][2];
#pragma unroll
  for (int g = 0; g < 4; ++g) {
    const float z = xor8(acc[g][2]);
    const float w2 = xor8(acc[g][3]);
    s[g][0] = grp ? z : acc[g][0];
    s[g][1] = grp ? w2 : acc[g][1];
  }
  float hv0, hv1;
#pragma unroll
  for (int v = 0; v < 2; ++v) {
    const float iv = sigm2(s[0][v]), fv = sigm2(s[1][v]);
    const float gv = tanh2(s[2][v]), ov = sigm2(s[3][v]);
    float &c = v ? cb : ca;
    c = fv * c + iv * gv;
    const float h = ov * tanh2(c * (2.f * LG2E));
    (v ? hv1 : hv0) = h;
  }
  split_pair(hv0, hv1, hpk, lpk);
}

// Layer-pipelined fused LSTM: 8 waves/block, 256 blocks (1/CU, 2 waves/SIMD).
// Waves 0-3 = layer0 at time i; waves 4-7 = layer1 at time i-1; ONE barrier/step
// (the HW scheduler overlaps A-pointwise with B-MFMA via free wave drift).
// h-exchange LDS: flat [layer(2)][parity(2)][hi|lo(2)][row=batch16][word=pair32],
// word idx XOR-swizzled by (row&7)<<2 -> B-frag = 1 aligned ds_read_b128/plane,
// zero bank conflicts. Rows 8-15 stay zero (batch cols 8-15 unused).
__global__ __launch_bounds__(512, 2) void lstm_pipe(
    const float* __restrict__ x,
    const float* __restrict__ w_ih0, const float* __restrict__ w_hh0,
    const float* __restrict__ b_ih0, const float* __restrict__ b_hh0,
    const float* __restrict__ w_ih1, const float* __restrict__ w_hh1,
    const float* __restrict__ b_ih1, const float* __restrict__ b_hh1,
    const float* __restrict__ w_out, const float* __restrict__ b_out,
    float* __restrict__ out) {
  __shared__ __align__(16) unsigned hpf[4096];  // 16 KiB

  const int tid = threadIdx.x;
  const int lane = tid & 63;
  const int wv = __builtin_amdgcn_readfirstlane(tid >> 6);  // 0..7
  const int isB = wv >> 2;   // 0 = layer0 group, 1 = layer1 group
  const int w = wv & 3;      // unit group [16w, 16w+16)
  const int q = lane >> 4;
  const int n16 = lane & 15;
  const int nb = lane & 7;
  const int grp = (lane >> 3) & 1;
  const int blk = blockIdx.x;

  for (int e = tid; e < 4096; e += 512) hpf[e] = 0u;

  // reader: word offsets within a row for kt=0 / kt=1 (swizzle-folded)
  const int sw4 = (n16 & 7) << 2;
  const int b0w = (4 * q) ^ sw4;       // kt=0
  const int b1w = b0w ^ 16;            // kt=1
  // writer: this lane owns units (u0, u0+1) for batch nb -> pair u0>>1
  const int u0 = 16 * w + 4 * q + 2 * grp;
  const int wroff = (isB ? 2048 : 0) + nb * 32 + ((u0 >> 1) ^ (nb << 2));

  // ---- weights -> AGPR overlay (bf16 hi/lo pack, exp2-domain pre-scale). ----
  // A-frag: lane holds A[m=n16][k=8q+j]; packed word = (elem_odd<<16)|elem_even.
  v4i wr[32];
  f32x4 biasf[4];
  {
    float vv[8];
    if (!isB) {
#pragma unroll
      for (int g = 0; g < 4; ++g) {
        const float gsc = (g == 2) ? 2.f * LG2E : LG2E;
        const int row = g * HID + 16 * w + n16;
#pragma unroll
        for (int j = 0; j < 8; ++j) {
          const int k = 8 * q + j;
          vv[j] = (k < NIN) ? w_ih0[row * NIN + k] * gsc : 0.f;
        }
        pack_frags(vv, WA_X(g, 0), WA_X(g, 1));
#pragma unroll
        for (int kt = 0; kt < 2; ++kt) {
#pragma unroll
          for (int j = 0; j < 8; ++j)
            vv[j] = w_hh0[row * HID + 32 * kt + 8 * q + j] * gsc;
          pack_frags(vv, WA_H(g, kt, 0), WA_H(g, kt, 1));
        }
#pragma unroll
        for (int r = 0; r < 4; ++r) {
          const int br = g * HID + 16 * w + 4 * q + r;
          biasf[g][r] = (b_ih0[br] + b_hh0[br]) * gsc;
        }
      }
    } else {
#pragma unroll
      for (int g = 0; g < 4; ++g) {
        const float gsc = (g == 2) ? 2.f * LG2E : LG2E;
        const int row = g * HID + 16 * w + n16;
#pragma unroll
        for (int kt = 0; kt < 2; ++kt) {
#pragma unroll
          for (int j = 0; j < 8; ++j)
            vv[j] = w_ih1[row * HID + 32 * kt + 8 * q + j] * gsc;
          pack_frags(vv, WB_Y(g, kt, 0), WB_Y(g, kt, 1));
#pragma unroll
          for (int j = 0; j < 8; ++j)
            vv[j] = w_hh1[row * HID + 32 * kt + 8 * q + j] * gsc;
          pack_frags(vv, WB_H(g, kt, 0), WB_H(g, kt, 1));
        }
#pragma unroll
        for (int r = 0; r < 4; ++r) {
          const int br = g * HID + 16 * w + 4 * q + r;
          biasf[g][r] = (b_ih1[br] + b_hh1[br]) * gsc;
        }
      }
    }
  }

  // ---- x streaming (A-waves): two contiguous dwordx4 per step (k = 8q..8q+7).
  // Pack-ahead: xhi/xlo always hold the CURRENT step's fragments; the pack for
  // step i+1 runs at the END of step i (loads issued a full step earlier), so a
  // step opens with ds_reads + 12 immediately-issueable x-MFMAs. ----
  const float* xp0 = x;
  const float* xp1 = x;
  int st0 = 0, st1 = 0;
  v4i xmask = {0, 0, 0, 0};
  f32x4 xva = {0.f, 0.f, 0.f, 0.f}, xvb = {0.f, 0.f, 0.f, 0.f};
  v4i xhi = {0, 0, 0, 0}, xlo = {0, 0, 0, 0};
  float ca = 0.f, cb = 0.f;
  if (!isB) {
    const int k0 = 8 * q;
    const bool v0 = (k0 + 3 < NIN);  // q <= 2
    const bool v1 = (k0 + 7 < NIN);  // q <= 1
    const float* xb = x + (size_t)(blk * 8 + nb) * T_SEQ * NIN;
    xp0 = v0 ? xb + k0 : x;          // invalid lanes park on x[0] (in-bounds, masked)
    xp1 = v1 ? xb + k0 + 4 : x;
    st0 = v0 ? NIN : 0;
    st1 = v1 ? NIN : 0;
#pragma unroll
    for (int d = 0; d < 4; ++d) {
      const unsigned m0 = (k0 + 2 * d < NIN) ? 0x0000ffffu : 0u;
      const unsigned m1 = (k0 + 2 * d + 1 < NIN) ? 0xffff0000u : 0u;
      xmask[d] = (int)(m0 | m1);
    }
    xva = *(const f32x4*)xp0;
    xvb = *(const f32x4*)xp1;
    xp0 += st0;
    xp1 += st1;
    pack_x(xva, xvb, xmask, xhi, xlo);  // fragments for step 0
  }

  __syncthreads();  // LDS zero-init visible

#pragma unroll 1
  for (int i = 0; i <= T_SEQ; ++i) {
    const int par = i & 1;
    if (!isB) {
      if (i < T_SEQ) {
        // ==== layer 0, time i: gates = b + Wx.x(i) + Wh.h0(i-1) ====
        const unsigned* r0 = hpf + (par ^ 1) * 1024 + n16 * 32;  // layer0
        v4i hh0 = *(const v4i*)(r0 + b0w);
        v4i hl0 = *(const v4i*)(r0 + 512 + b0w);
        v4i hh1 = *(const v4i*)(r0 + b1w);
        v4i hl1 = *(const v4i*)(r0 + 512 + b1w);
        const bool pf = i < T_SEQ - 1;
        if (pf) {  // prefetch x(i+1); stays in flight across BAR()
          xva = *(const f32x4*)xp0;
          xvb = *(const f32x4*)xp1;
          xp0 += st0;
          xp1 += st1;
        }
        f32x4 acc[4];
#pragma unroll
        for (int g = 0; g < 4; ++g) acc[g] = biasf[g];
        // x products first: no LDS dependency, covers the ds_read latency
#pragma unroll
        for (int g = 0; g < 4; ++g) {
          MFMA(acc[g], WA_X(g, 0), xhi);
          MFMA(acc[g], WA_X(g, 0), xlo);
          MFMA(acc[g], WA_X(g, 1), xhi);
        }
#pragma unroll
        for (int g = 0; g < 4; ++g) {
          MFMA(acc[g], WA_H(g, 0, 0), hh0);
          MFMA(acc[g], WA_H(g, 0, 0), hl0);
          MFMA(acc[g], WA_H(g, 0, 1), hh0);
        }
#pragma unroll
        for (int g = 0; g < 4; ++g) {
          MFMA(acc[g], WA_H(g, 1, 0), hh1);
          MFMA(acc[g], WA_H(g, 1, 0), hl1);
          MFMA(acc[g], WA_H(g, 1, 1), hh1);
        }
        unsigned hpk, lpk;
        pointwise(acc, grp, ca, cb, hpk, lpk);
        hpf[wroff + par * 1024] = hpk;
        hpf[wroff + par * 1024 + 512] = lpk;
        if (pf) pack_x(xva, xvb, xmask, xhi, xlo);  // fragments for step i+1
      }
    } else {
      if (i >= 1) {
        // ==== layer 1, time i-1: gates = b + Wy.h0(i-1) + Wh.h1(i-2) ====
        const unsigned* r0 = hpf + (par ^ 1) * 1024 + n16 * 32;         // layer0 (y)
        const unsigned* r1 = hpf + 2048 + (par ^ 1) * 1024 + n16 * 32;  // layer1 (h)
        v4i yh0 = *(const v4i*)(r0 + b0w);
        v4i yl0 = *(const v4i*)(r0 + 512 + b0w);
        v4i yh1 = *(const v4i*)(r0 + b1w);
        v4i yl1 = *(const v4i*)(r0 + 512 + b1w);
        v4i hh0 = *(const v4i*)(r1 + b0w);
        v4i hl0 = *(const v4i*)(r1 + 512 + b0w);
        v4i hh1 = *(const v4i*)(r1 + b1w);
        v4i hl1 = *(const v4i*)(r1 + 512 + b1w);
        f32x4 acc[4];
#pragma unroll
        for (int g = 0; g < 4; ++g) acc[g] = biasf[g];
#pragma unroll
        for (int g = 0; g < 4; ++g) {
          MFMA(acc[g], WB_Y(g, 0, 0), yh0);
          MFMA(acc[g], WB_Y(g, 0, 0), yl0);
          MFMA(acc[g], WB_Y(g, 0, 1), yh0);
        }
#pragma unroll
        for (int g = 0; g < 4; ++g) {
          MFMA(acc[g], WB_H(g, 0, 0), hh0);
          MFMA(acc[g], WB_H(g, 0, 0), hl0);
          MFMA(acc[g], WB_H(g, 0, 1), hh0);
        }
#pragma unroll
        for (int g = 0; g < 4; ++g) {
          MFMA(acc[g], WB_Y(g, 1, 0), yh1);
          MFMA(acc[g], WB_Y(g, 1, 0), yl1);
          MFMA(acc[g], WB_Y(g, 1, 1), yh1);
        }
#pragma unroll
        for (int g = 0; g < 4; ++g) {
          MFMA(acc[g], WB_H(g, 1, 0), hh1);
          MFMA(acc[g], WB_H(g, 1, 0), hl1);
          MFMA(acc[g], WB_H(g, 1, 1), hh1);
        }
        unsigned hpk, lpk;
        pointwise(acc, grp, ca, cb, hpk, lpk);
        hpf[wroff + par * 1024] = hpk;
        hpf[wroff + par * 1024 + 512] = lpk;
      }
    }
    BAR();
  }

  // ---- projection: out[b] = h1(511) @ w_out^T + b_out; h1(511) at layer1/par0 ----
  if (tid < 8 * OUT_N) {
    const int b = tid / OUT_N, j = tid - b * OUT_N;
    float s = b_out[j];
    const unsigned* hrow = hpf + 2048 + b * 32;  // layer1, par0, hi; lo at +512
    const int swb = b << 2;                      // b < 8
    for (int p = 0; p < 32; ++p) {
      const int wsw = p ^ swb;
      const unsigned hw = hrow[wsw];
      const unsigned lw = hrow[wsw + 512];
      const float h0v = __uint_as_float(hw << 16) + __uint_as_float(lw << 16);
      const float h1v = __uint_as_float(hw & 0xffff0000u) + __uint_as_float(lw & 0xffff0000u);
      s = fmaf(w_out[j * HID + 2 * p], h0v, s);
      s = fmaf(w_out[j * HID + 2 * p + 1], h1v, s);
    }
    out[(blk * 8 + b) * OUT_N + j] = s;
  }
}

extern "C" void kernel_launch(void* const* d_in, const int* in_sizes, int n_in,
                              void* d_out, int out_size, void* d_ws, size_t ws_size,
                              hipStream_t stream) {
  const float* x = (const float*)d_in[0];
  const float* w_ih0 = (const float*)d_in[1];
  const float* w_hh0 = (const float*)d_in[2];
  const float* b_ih0 = (const float*)d_in[3];
  const float* b_hh0 = (const float*)d_in[4];
  const float* w_ih1 = (const float*)d_in[5];
  const float* w_hh1 = (const float*)d_in[6];
  const float* b_ih1 = (const float*)d_in[7];
  const float* b_hh1 = (const float*)d_in[8];
  const float* w_out = (const float*)d_in[9];
  const float* b_out = (const float*)d_in[10];
  float* out = (float*)d_out;

  hipLaunchKernelGGL(lstm_pipe, dim3(2048 / 8), dim3(512), 0, stream,
                     x, w_ih0, w_hh0, b_ih0, b_hh0,
                     w_ih1, w_hh1, b_ih1, b_hh1, w_out, b_out, out);
}

// Round 8
// 665.453 us; speedup vs baseline: 1.2042x; 1.0183x over previous
//
#include <hip/hip_runtime.h>

#define T_SEQ 512
#define HID 64
#define NIN 20
#define OUT_N 5

typedef float f32x4 __attribute__((ext_vector_type(4)));
typedef int v4i __attribute__((ext_vector_type(4)));

#if __has_builtin(__builtin_amdgcn_exp2f)
#define EXP2(x) __builtin_amdgcn_exp2f(x)
#else
#define EXP2(x) exp2f(x)
#endif

#define LG2E 1.44269504088896340736f

// D = A*B + D, A from AGPR. VOLATILE: pins the round-robin accumulator
// interleave (dep distance 4) so the scheduler can't re-cluster same-acc
// chains back-to-back (MFMA dep latency >> issue interval at 2 waves/SIMD).
#define MFMA(acc, A, B) \
  asm volatile("v_mfma_f32_16x16x32_bf16 %0, %1, %2, %0" : "+v"(acc) : "a"(A), "v"(B))

// Raw barrier: drain LDS (write visibility) but leave global prefetch in flight.
#define BAR() asm volatile("s_waitcnt lgkmcnt(0)\n\ts_barrier" ::: "memory")

// Weight-register overlay (A-waves use 24 slots, B-waves 32).
#define WA_X(g, hl) wr[2 * (g) + (hl)]
#define WA_H(g, kt, hl) wr[8 + 4 * (g) + 2 * (kt) + (hl)]
#define WB_Y(g, kt, hl) wr[4 * (g) + 2 * (kt) + (hl)]
#define WB_H(g, kt, hl) wr[16 + 4 * (g) + 2 * (kt) + (hl)]

// HW packed f32->bf16 conversion (gfx950; no builtin -- inline asm).
__device__ __forceinline__ unsigned cvt_pk_bf16(float a, float b) {
  unsigned r;
  asm("v_cvt_pk_bf16_f32 %0, %1, %2" : "=v"(r) : "v"(a), "v"(b));
  return r;  // low16 = bf16(a), high16 = bf16(b)
}
// hi/lo pair split: hw = packed bf16(a,b); lw = packed bf16 of exact residuals.
__device__ __forceinline__ void split_pair(float a, float b, unsigned &hw, unsigned &lw) {
  hw = cvt_pk_bf16(a, b);
  const float ah = __uint_as_float(hw << 16);
  const float bh = __uint_as_float(hw & 0xffff0000u);
  lw = cvt_pk_bf16(a - ah, b - bh);
}
__device__ __forceinline__ void pack_frags(const float* v, v4i &hi, v4i &lo) {
#pragma unroll
  for (int d = 0; d < 4; ++d) {
    unsigned hw, lw;
    split_pair(v[2 * d], v[2 * d + 1], hw, lw);
    hi[d] = (int)hw;
    lo[d] = (int)lw;
  }
}
// Pack the two x dwordx4 halves directly into masked MFMA fragments.
__device__ __forceinline__ void pack_x(const f32x4 &a, const f32x4 &b, const v4i &m,
                                       v4i &hi, v4i &lo) {
  unsigned hw, lw;
  split_pair(a[0], a[1], hw, lw); hi[0] = (int)(hw & m[0]); lo[0] = (int)(lw & m[0]);
  split_pair(a[2], a[3], hw, lw); hi[1] = (int)(hw & m[1]); lo[1] = (int)(lw & m[1]);
  split_pair(b[0], b[1], hw, lw); hi[2] = (int)(hw & m[2]); lo[2] = (int)(lw & m[2]);
  split_pair(b[2], b[3], hw, lw); hi[3] = (int)(hw & m[3]); lo[3] = (int)(lw & m[3]);
}

// lane L <- lane L^8, on the VALU pipe (DPP row_ror:8; (l+8)%16 == l^8).
__device__ __forceinline__ float xor8(float v) {
  return __int_as_float(
      __builtin_amdgcn_mov_dpp(__float_as_int(v), 0x128, 0xf, 0xf, true));
}

// Gates arrive pre-scaled: sigmoid gates by log2(e), tanh gate by 2*log2(e).
__device__ __forceinline__ float sigm2(float v) {
  return __builtin_amdgcn_rcpf(1.f + EXP2(-v));
}
__device__ __forceinline__ float tanh2(float v) {
  float a = fabsf(v), e = EXP2(-a);
  return copysignf((1.f - e) * __builtin_amdgcn_rcpf(1.f + e), v);
}

// Split pointwise: lanes n16<8 do D-rows r=0,1; lanes n16>=8 take r=2,3 of the
// partner (DPP xor8) for batch nb=lane&7. Bias (pre-scaled) is in the acc init.
__device__ __forceinline__ void pointwise(const f32x4* acc, int grp, float &ca, float &cb,
                                          unsigned &hpk, unsigned &lpk) {
  float s[4][2];
#pragma unroll
  for (int g = 0; g < 4; ++g) {
    const float z = xor8(acc[g][2]);
    const float w2 = xor8(acc[g][3]);
    s[g][0] = grp ? z : acc[g][0];
    s[g][1] = grp ? w2 : acc[g][1];
  }
  float hv0, hv1;
#pragma unroll
  for (int v = 0; v < 2; ++v) {
    const float iv = sigm2(s[0][v]), fv = sigm2(s[1][v]);
    const float gv = tanh2(s[2][v]), ov = sigm2(s[3][v]);
    float &c = v ? cb : ca;
    c = fmaf(fv, c, iv * gv);
    const float h = ov * tanh2(c * (2.f * LG2E));
    (v ? hv1 : hv0) = h;
  }
  split_pair(hv0, hv1, hpk, lpk);
}

// Layer-pipelined fused LSTM: 8 waves/block, 256 blocks (1/CU, 2 waves/SIMD).
// Waves 0-3 = layer0 at time i; waves 4-7 = layer1 at time i-1; ONE barrier/step.
// MFMA issue order: product-outer, g-inner (round-robin over the 4 accumulator
// chains) -- dep distance 4 keeps the matrix pipe fed at 2 waves/SIMD.
// h-exchange LDS: flat [layer(2)][parity(2)][hi|lo(2)][row=batch16][word=pair32],
// word idx XOR-swizzled by (row&7)<<2 -> B-frag = 1 aligned ds_read_b128/plane.
__global__ __launch_bounds__(512, 2) void lstm_pipe(
    const float* __restrict__ x,
    const float* __restrict__ w_ih0, const float* __restrict__ w_hh0,
    const float* __restrict__ b_ih0, const float* __restrict__ b_hh0,
    const float* __restrict__ w_ih1, const float* __restrict__ w_hh1,
    const float* __restrict__ b_ih1, const float* __restrict__ b_hh1,
    const float* __restrict__ w_out, const float* __restrict__ b_out,
    float* __restrict__ out) {
  __shared__ __align__(16) unsigned hpf[4096];  // 16 KiB

  const int tid = threadIdx.x;
  const int lane = tid & 63;
  const int wv = __builtin_amdgcn_readfirstlane(tid >> 6);  // 0..7
  const int isB = wv >> 2;   // 0 = layer0 group, 1 = layer1 group
  const int w = wv & 3;      // unit group [16w, 16w+16)
  const int q = lane >> 4;
  const int n16 = lane & 15;
  const int nb = lane & 7;
  const int grp = (lane >> 3) & 1;
  const int blk = blockIdx.x;

  for (int e = tid; e < 4096; e += 512) hpf[e] = 0u;

  // reader: word offsets within a row for kt=0 / kt=1 (swizzle-folded)
  const int sw4 = (n16 & 7) << 2;
  const int b0w = (4 * q) ^ sw4;       // kt=0
  const int b1w = b0w ^ 16;            // kt=1
  // writer: this lane owns units (u0, u0+1) for batch nb -> pair u0>>1
  const int u0 = 16 * w + 4 * q + 2 * grp;
  const int wroff = (isB ? 2048 : 0) + nb * 32 + ((u0 >> 1) ^ (nb << 2));

  // ---- weights -> AGPR overlay (bf16 hi/lo pack, exp2-domain pre-scale). ----
  v4i wr[32];
  f32x4 biasf[4];
  {
    float vv[8];
    if (!isB) {
#pragma unroll
      for (int g = 0; g < 4; ++g) {
        const float gsc = (g == 2) ? 2.f * LG2E : LG2E;
        const int row = g * HID + 16 * w + n16;
#pragma unroll
        for (int j = 0; j < 8; ++j) {
          const int k = 8 * q + j;
          vv[j] = (k < NIN) ? w_ih0[row * NIN + k] * gsc : 0.f;
        }
        pack_frags(vv, WA_X(g, 0), WA_X(g, 1));
#pragma unroll
        for (int kt = 0; kt < 2; ++kt) {
#pragma unroll
          for (int j = 0; j < 8; ++j)
            vv[j] = w_hh0[row * HID + 32 * kt + 8 * q + j] * gsc;
          pack_frags(vv, WA_H(g, kt, 0), WA_H(g, kt, 1));
        }
#pragma unroll
        for (int r = 0; r < 4; ++r) {
          const int br = g * HID + 16 * w + 4 * q + r;
          biasf[g][r] = (b_ih0[br] + b_hh0[br]) * gsc;
        }
      }
    } else {
#pragma unroll
      for (int g = 0; g < 4; ++g) {
        const float gsc = (g == 2) ? 2.f * LG2E : LG2E;
        const int row = g * HID + 16 * w + n16;
#pragma unroll
        for (int kt = 0; kt < 2; ++kt) {
#pragma unroll
          for (int j = 0; j < 8; ++j)
            vv[j] = w_ih1[row * HID + 32 * kt + 8 * q + j] * gsc;
          pack_frags(vv, WB_Y(g, kt, 0), WB_Y(g, kt, 1));
#pragma unroll
          for (int j = 0; j < 8; ++j)
            vv[j] = w_hh1[row * HID + 32 * kt + 8 * q + j] * gsc;
          pack_frags(vv, WB_H(g, kt, 0), WB_H(g, kt, 1));
        }
#pragma unroll
        for (int r = 0; r < 4; ++r) {
          const int br = g * HID + 16 * w + 4 * q + r;
          biasf[g][r] = (b_ih1[br] + b_hh1[br]) * gsc;
        }
      }
    }
  }

  // ---- x streaming (A-waves): two contiguous dwordx4 per step (k = 8q..8q+7).
  // Pack-ahead: xhi/xlo hold the CURRENT step's fragments. ----
  const float* xp0 = x;
  const float* xp1 = x;
  int st0 = 0, st1 = 0;
  v4i xmask = {0, 0, 0, 0};
  f32x4 xva = {0.f, 0.f, 0.f, 0.f}, xvb = {0.f, 0.f, 0.f, 0.f};
  v4i xhi = {0, 0, 0, 0}, xlo = {0, 0, 0, 0};
  float ca = 0.f, cb = 0.f;
  if (!isB) {
    const int k0 = 8 * q;
    const bool v0 = (k0 + 3 < NIN);  // q <= 2
    const bool v1 = (k0 + 7 < NIN);  // q <= 1
    const float* xb = x + (size_t)(blk * 8 + nb) * T_SEQ * NIN;
    xp0 = v0 ? xb + k0 : x;          // invalid lanes park on x[0] (in-bounds, masked)
    xp1 = v1 ? xb + k0 + 4 : x;
    st0 = v0 ? NIN : 0;
    st1 = v1 ? NIN : 0;
#pragma unroll
    for (int d = 0; d < 4; ++d) {
      const unsigned m0 = (k0 + 2 * d < NIN) ? 0x0000ffffu : 0u;
      const unsigned m1 = (k0 + 2 * d + 1 < NIN) ? 0xffff0000u : 0u;
      xmask[d] = (int)(m0 | m1);
    }
    xva = *(const f32x4*)xp0;
    xvb = *(const f32x4*)xp1;
    xp0 += st0;
    xp1 += st1;
    pack_x(xva, xvb, xmask, xhi, xlo);  // fragments for step 0
  }

  __syncthreads();  // LDS zero-init visible

#pragma unroll 1
  for (int i = 0; i <= T_SEQ; ++i) {
    const int par = i & 1;
    if (!isB) {
      if (i < T_SEQ) {
        // ==== layer 0, time i: gates = b + Wx.x(i) + Wh.h0(i-1) ====
        const unsigned* r0 = hpf + (par ^ 1) * 1024 + n16 * 32;  // layer0
        v4i hh0 = *(const v4i*)(r0 + b0w);
        v4i hl0 = *(const v4i*)(r0 + 512 + b0w);
        v4i hh1 = *(const v4i*)(r0 + b1w);
        v4i hl1 = *(const v4i*)(r0 + 512 + b1w);
        const bool pf = i < T_SEQ - 1;
        if (pf) {  // prefetch x(i+1); stays in flight across BAR()
          xva = *(const f32x4*)xp0;
          xvb = *(const f32x4*)xp1;
          xp0 += st0;
          xp1 += st1;
        }
        f32x4 acc[4];
#pragma unroll
        for (int g = 0; g < 4; ++g) acc[g] = biasf[g];
        // Round-robin over the 4 acc chains (dep distance 4). x products first:
        // no LDS dependency, covers the ds_read latency.
#pragma unroll
        for (int g = 0; g < 4; ++g) MFMA(acc[g], WA_X(g, 0), xhi);
#pragma unroll
        for (int g = 0; g < 4; ++g) MFMA(acc[g], WA_X(g, 0), xlo);
#pragma unroll
        for (int g = 0; g < 4; ++g) MFMA(acc[g], WA_X(g, 1), xhi);
#pragma unroll
        for (int g = 0; g < 4; ++g) MFMA(acc[g], WA_H(g, 0, 0), hh0);
#pragma unroll
        for (int g = 0; g < 4; ++g) MFMA(acc[g], WA_H(g, 0, 0), hl0);
#pragma unroll
        for (int g = 0; g < 4; ++g) MFMA(acc[g], WA_H(g, 0, 1), hh0);
#pragma unroll
        for (int g = 0; g < 4; ++g) MFMA(acc[g], WA_H(g, 1, 0), hh1);
#pragma unroll
        for (int g = 0; g < 4; ++g) MFMA(acc[g], WA_H(g, 1, 0), hl1);
#pragma unroll
        for (int g = 0; g < 4; ++g) MFMA(acc[g], WA_H(g, 1, 1), hh1);
        unsigned hpk, lpk;
        pointwise(acc, grp, ca, cb, hpk, lpk);
        hpf[wroff + par * 1024] = hpk;
        hpf[wroff + par * 1024 + 512] = lpk;
        if (pf) pack_x(xva, xvb, xmask, xhi, xlo);  // fragments for step i+1
      }
    } else {
      if (i >= 1) {
        // ==== layer 1, time i-1: gates = b + Wy.h0(i-1) + Wh.h1(i-2) ====
        const unsigned* r0 = hpf + (par ^ 1) * 1024 + n16 * 32;         // layer0 (y)
        const unsigned* r1 = hpf + 2048 + (par ^ 1) * 1024 + n16 * 32;  // layer1 (h)
        v4i yh0 = *(const v4i*)(r0 + b0w);
        v4i yl0 = *(const v4i*)(r0 + 512 + b0w);
        v4i yh1 = *(const v4i*)(r0 + b1w);
        v4i yl1 = *(const v4i*)(r0 + 512 + b1w);
        v4i hh0 = *(const v4i*)(r1 + b0w);
        v4i hl0 = *(const v4i*)(r1 + 512 + b0w);
        v4i hh1 = *(const v4i*)(r1 + b1w);
        v4i hl1 = *(const v4i*)(r1 + 512 + b1w);
        f32x4 acc[4];
#pragma unroll
        for (int g = 0; g < 4; ++g) acc[g] = biasf[g];
        // Round-robin over the 4 acc chains (dep distance 4).
#pragma unroll
        for (int g = 0; g < 4; ++g) MFMA(acc[g], WB_Y(g, 0, 0), yh0);
#pragma unroll
        for (int g = 0; g < 4; ++g) MFMA(acc[g], WB_Y(g, 0, 0), yl0);
#pragma unroll
        for (int g = 0; g < 4; ++g) MFMA(acc[g], WB_Y(g, 0, 1), yh0);
#pragma unroll
        for (int g = 0; g < 4; ++g) MFMA(acc[g], WB_H(g, 0, 0), hh0);
#pragma unroll
        for (int g = 0; g < 4; ++g) MFMA(acc[g], WB_H(g, 0, 0), hl0);
#pragma unroll
        for (int g = 0; g < 4; ++g) MFMA(acc[g], WB_H(g, 0, 1), hh0);
#pragma unroll
        for (int g = 0; g < 4; ++g) MFMA(acc[g], WB_Y(g, 1, 0), yh1);
#pragma unroll
        for (int g = 0; g < 4; ++g) MFMA(acc[g], WB_Y(g, 1, 0), yl1);
#pragma unroll
        for (int g = 0; g < 4; ++g) MFMA(acc[g], WB_Y(g, 1, 1), yh1);
#pragma unroll
        for (int g = 0; g < 4; ++g) MFMA(acc[g], WB_H(g, 1, 0), hh1);
#pragma unroll
        for (int g = 0; g < 4; ++g) MFMA(acc[g], WB_H(g, 1, 0), hl1);
#pragma unroll
        for (int g = 0; g < 4; ++g) MFMA(acc[g], WB_H(g, 1, 1), hh1);
        unsigned hpk, lpk;
        pointwise(acc, grp, ca, cb, hpk, lpk);
        hpf[wroff + par * 1024] = hpk;
        hpf[wroff + par * 1024 + 512] = lpk;
      }
    }
    BAR();
  }

  // ---- projection: out[b] = h1(511) @ w_out^T + b_out; h1(511) at layer1/par0 ----
  if (tid < 8 * OUT_N) {
    const int b = tid / OUT_N, j = tid - b * OUT_N;
    float s = b_out[j];
    const unsigned* hrow = hpf + 2048 + b * 32;  // layer1, par0, hi; lo at +512
    const int swb = b << 2;                      // b < 8
    for (int p = 0; p < 32; ++p) {
      const int wsw = p ^ swb;
      const unsigned hw = hrow[wsw];
      const unsigned lw = hrow[wsw + 512];
      const float h0v = __uint_as_float(hw << 16) + __uint_as_float(lw << 16);
      const float h1v = __uint_as_float(hw & 0xffff0000u) + __uint_as_float(lw & 0xffff0000u);
      s = fmaf(w_out[j * HID + 2 * p], h0v, s);
      s = fmaf(w_out[j * HID + 2 * p + 1], h1v, s);
    }
    out[(blk * 8 + b) * OUT_N + j] = s;
  }
}

extern "C" void kernel_launch(void* const* d_in, const int* in_sizes, int n_in,
                              void* d_out, int out_size, void* d_ws, size_t ws_size,
                              hipStream_t stream) {
  const float* x = (const float*)d_in[0];
  const float* w_ih0 = (const float*)d_in[1];
  const float* w_hh0 = (const float*)d_in[2];
  const float* b_ih0 = (const float*)d_in[3];
  const float* b_hh0 = (const float*)d_in[4];
  const float* w_ih1 = (const float*)d_in[5];
  const float* w_hh1 = (const float*)d_in[6];
  const float* b_ih1 = (const float*)d_in[7];
  const float* b_hh1 = (const float*)d_in[8];
  const float* w_out = (const float*)d_in[9];
  const float* b_out = (const float*)d_in[10];
  float* out = (float*)d_out;

  hipLaunchKernelGGL(lstm_pipe, dim3(2048 / 8), dim3(512), 0, stream,
                     x, w_ih0, w_hh0, b_ih0, b_hh0,
                     w_ih1, w_hh1, b_ih1, b_hh1, w_out, b_out, out);
}

// Round 13
// 657.086 us; speedup vs baseline: 1.2196x; 1.0127x over previous
//
#include <hip/hip_runtime.h>

#define T_SEQ 512
#define HID 64
#define NIN 20
#define OUT_N 5

typedef float f32x4 __attribute__((ext_vector_type(4)));
typedef int v4i __attribute__((ext_vector_type(4)));

#if __has_builtin(__builtin_amdgcn_exp2f)
#define EXP2(x) __builtin_amdgcn_exp2f(x)
#else
#define EXP2(x) exp2f(x)
#endif

#define LG2E 1.44269504088896340736f

// D = A*B + D, A from AGPR. Volatile pins the round-robin acc interleave.
#define MFMA(acc, A, B) \
  asm volatile("v_mfma_f32_16x16x32_bf16 %0, %1, %2, %0" : "+v"(acc) : "a"(A), "v"(B))

// Raw barrier: drain LDS (write visibility) but leave global prefetch in flight.
#define BAR() asm volatile("s_waitcnt lgkmcnt(0)\n\ts_barrier" ::: "memory")

// Weight-register overlay (A-waves use 24 slots, B-waves 32).
#define WA_X(g, hl) wr[2 * (g) + (hl)]
#define WA_H(g, kt, hl) wr[8 + 4 * (g) + 2 * (kt) + (hl)]
#define WB_Y(g, kt, hl) wr[4 * (g) + 2 * (kt) + (hl)]
#define WB_H(g, kt, hl) wr[16 + 4 * (g) + 2 * (kt) + (hl)]

// HW packed f32->bf16 conversion (gfx950; no builtin -- inline asm).
__device__ __forceinline__ unsigned cvt_pk_bf16(float a, float b) {
  unsigned r;
  asm("v_cvt_pk_bf16_f32 %0, %1, %2" : "=v"(r) : "v"(a), "v"(b));
  return r;  // low16 = bf16(a), high16 = bf16(b)
}
// hi/lo pair split: hw = packed bf16(a,b); lw = packed bf16 of exact residuals.
__device__ __forceinline__ void split_pair(float a, float b, unsigned &hw, unsigned &lw) {
  hw = cvt_pk_bf16(a, b);
  const float ah = __uint_as_float(hw << 16);
  const float bh = __uint_as_float(hw & 0xffff0000u);
  lw = cvt_pk_bf16(a - ah, b - bh);
}
__device__ __forceinline__ void pack_frags(const float* v, v4i &hi, v4i &lo) {
#pragma unroll
  for (int d = 0; d < 4; ++d) {
    unsigned hw, lw;
    split_pair(v[2 * d], v[2 * d + 1], hw, lw);
    hi[d] = (int)hw;
    lo[d] = (int)lw;
  }
}
// Pack the two x dwordx4 halves directly into masked MFMA fragments.
__device__ __forceinline__ void pack_x(const f32x4 &a, const f32x4 &b, const v4i &m,
                                       v4i &hi, v4i &lo) {
  unsigned hw, lw;
  split_pair(a[0], a[1], hw, lw); hi[0] = (int)(hw & m[0]); lo[0] = (int)(lw & m[0]);
  split_pair(a[2], a[3], hw, lw); hi[1] = (int)(hw & m[1]); lo[1] = (int)(lw & m[1]);
  split_pair(b[0], b[1], hw, lw); hi[2] = (int)(hw & m[2]); lo[2] = (int)(lw & m[2]);
  split_pair(b[2], b[3], hw, lw); hi[3] = (int)(hw & m[3]); lo[3] = (int)(lw & m[3]);
}

// Gates arrive pre-scaled: sigmoid gates by log2(e), tanh gate by 2*log2(e).
__device__ __forceinline__ float sigm2(float v) {
  return __builtin_amdgcn_rcpf(1.f + EXP2(-v));
}
__device__ __forceinline__ float tanh2(float v) {
  float a = fabsf(v), e = EXP2(-a);
  return copysignf((1.f - e) * __builtin_amdgcn_rcpf(1.f + e), v);
}

// lane L <- lane L^8, on the VALU pipe (DPP row_ror:8; (l+8)%16 == l^8).
__device__ __forceinline__ float xor8(float v) {
  return __int_as_float(
      __builtin_amdgcn_mov_dpp(__float_as_int(v), 0x128, 0xf, 0xf, true));
}

// Split pointwise: lanes n16<8 do D-rows r=0,1; lanes n16>=8 take r=2,3 of the
// partner (DPP xor8) for batch nb=lane&7. Bias (pre-scaled) is in the acc init.
__device__ __forceinline__ void pointwise(const f32x4* acc, int grp, float &ca, float &cb,
                                          unsigned &hpk, unsigned &lpk) {
  float s[4][2];
#pragma unroll
  for (int g = 0; g < 4; ++g) {
    const float z = xor8(acc[g][2]);
    const float w2 = xor8(acc[g][3]);
    s[g][0] = grp ? z : acc[g][0];
    s[g][1] = grp ? w2 : acc[g][1];
  }
  float hv0, hv1;
#pragma unroll
  for (int v = 0; v < 2; ++v) {
    const float iv = sigm2(s[0][v]), fv = sigm2(s[1][v]);
    const float gv = tanh2(s[2][v]), ov = sigm2(s[3][v]);
    float &c = v ? cb : ca;
    c = fmaf(fv, c, iv * gv);
    const float h = ov * tanh2(c * (2.f * LG2E));
    (v ? hv1 : hv0) = h;
  }
  split_pair(hv0, hv1, hpk, lpk);
}

// Layer-pipelined fused LSTM: 8 waves/block, 256 blocks (1/CU, 2 waves/SIMD).
// Waves 0-3 = layer0 at time i; waves 4-7 = layer1 at time i-1; ONE barrier/step.
//
// T5 setprio (this round's single delta vs the 665us r8 kernel; data path is
// BIT-IDENTICAL -- setprio is a pure scheduler arbitration hint): the A/B wave
// pair on each SIMD is role-split (one issues MFMAs while the other runs its
// serial pointwise/exp tail). Raising priority during the MFMA block and
// dropping it for the pointwise lets the MFMA-holding wave win issue slots
// exactly when its partner doesn't need them (m191 mechanism).
//
// h-exchange LDS: flat [layer(2)][parity(2)][hi|lo(2)][row=batch16][word=pair32],
// word idx XOR-swizzled by (row&7)<<2 -> B-frag = 1 aligned ds_read_b128/plane,
// zero bank conflicts. Rows 8-15 stay zero (batch cols 8-15 unused).
__global__ __launch_bounds__(512, 2) void lstm_pipe(
    const float* __restrict__ x,
    const float* __restrict__ w_ih0, const float* __restrict__ w_hh0,
    const float* __restrict__ b_ih0, const float* __restrict__ b_hh0,
    const float* __restrict__ w_ih1, const float* __restrict__ w_hh1,
    const float* __restrict__ b_ih1, const float* __restrict__ b_hh1,
    const float* __restrict__ w_out, const float* __restrict__ b_out,
    float* __restrict__ out) {
  __shared__ __align__(16) unsigned hpf[4096];  // 16 KiB

  const int tid = threadIdx.x;
  const int lane = tid & 63;
  const int wv = __builtin_amdgcn_readfirstlane(tid >> 6);  // 0..7
  const int isB = wv >> 2;   // 0 = layer0 group, 1 = layer1 group
  const int w = wv & 3;      // unit group [16w, 16w+16)
  const int q = lane >> 4;
  const int n16 = lane & 15;
  const int nb = lane & 7;
  const int grp = (lane >> 3) & 1;
  const int blk = blockIdx.x;

  for (int e = tid; e < 4096; e += 512) hpf[e] = 0u;

  // reader: word offsets within a row for kt=0 / kt=1 (swizzle-folded)
  const int sw4 = (n16 & 7) << 2;
  const int b0w = (4 * q) ^ sw4;       // kt=0
  const int b1w = b0w ^ 16;            // kt=1
  // writer: this lane owns units (u0, u0+1) for batch nb -> pair u0>>1
  const int u0 = 16 * w + 4 * q + 2 * grp;
  const int wroff = (isB ? 2048 : 0) + nb * 32 + ((u0 >> 1) ^ (nb << 2));

  // ---- weights -> AGPR overlay (bf16 hi/lo pack, exp2-domain pre-scale). ----
  v4i wr[32];
  f32x4 biasf[4];
  {
    float vv[8];
    if (!isB) {
#pragma unroll
      for (int g = 0; g < 4; ++g) {
        const float gsc = (g == 2) ? 2.f * LG2E : LG2E;
        const int row = g * HID + 16 * w + n16;
#pragma unroll
        for (int j = 0; j < 8; ++j) {
          const int k = 8 * q + j;
          vv[j] = (k < NIN) ? w_ih0[row * NIN + k] * gsc : 0.f;
        }
        pack_frags(vv, WA_X(g, 0), WA_X(g, 1));
#pragma unroll
        for (int kt = 0; kt < 2; ++kt) {
#pragma unroll
          for (int j = 0; j < 8; ++j)
            vv[j] = w_hh0[row * HID + 32 * kt + 8 * q + j] * gsc;
          pack_frags(vv, WA_H(g, kt, 0), WA_H(g, kt, 1));
        }
#pragma unroll
        for (int r = 0; r < 4; ++r) {
          const int br = g * HID + 16 * w + 4 * q + r;
          biasf[g][r] = (b_ih0[br] + b_hh0[br]) * gsc;
        }
      }
    } else {
#pragma unroll
      for (int g = 0; g < 4; ++g) {
        const float gsc = (g == 2) ? 2.f * LG2E : LG2E;
        const int row = g * HID + 16 * w + n16;
#pragma unroll
        for (int kt = 0; kt < 2; ++kt) {
#pragma unroll
          for (int j = 0; j < 8; ++j)
            vv[j] = w_ih1[row * HID + 32 * kt + 8 * q + j] * gsc;
          pack_frags(vv, WB_Y(g, kt, 0), WB_Y(g, kt, 1));
#pragma unroll
          for (int j = 0; j < 8; ++j)
            vv[j] = w_hh1[row * HID + 32 * kt + 8 * q + j] * gsc;
          pack_frags(vv, WB_H(g, kt, 0), WB_H(g, kt, 1));
        }
#pragma unroll
        for (int r = 0; r < 4; ++r) {
          const int br = g * HID + 16 * w + 4 * q + r;
          biasf[g][r] = (b_ih1[br] + b_hh1[br]) * gsc;
        }
      }
    }
  }

  // ---- x streaming (A-waves): two contiguous dwordx4 per step (k = 8q..8q+7).
  // Pack-ahead: xhi/xlo hold the CURRENT step's fragments. ----
  const float* xp0 = x;
  const float* xp1 = x;
  int st0 = 0, st1 = 0;
  v4i xmask = {0, 0, 0, 0};
  f32x4 xva = {0.f, 0.f, 0.f, 0.f}, xvb = {0.f, 0.f, 0.f, 0.f};
  v4i xhi = {0, 0, 0, 0}, xlo = {0, 0, 0, 0};
  float ca = 0.f, cb = 0.f;
  if (!isB) {
    const int k0 = 8 * q;
    const bool v0 = (k0 + 3 < NIN);  // q <= 2
    const bool v1 = (k0 + 7 < NIN);  // q <= 1
    const float* xb = x + (size_t)(blk * 8 + nb) * T_SEQ * NIN;
    xp0 = v0 ? xb + k0 : x;          // invalid lanes park on x[0] (in-bounds, masked)
    xp1 = v1 ? xb + k0 + 4 : x;
    st0 = v0 ? NIN : 0;
    st1 = v1 ? NIN : 0;
#pragma unroll
    for (int d = 0; d < 4; ++d) {
      const unsigned m0 = (k0 + 2 * d < NIN) ? 0x0000ffffu : 0u;
      const unsigned m1 = (k0 + 2 * d + 1 < NIN) ? 0xffff0000u : 0u;
      xmask[d] = (int)(m0 | m1);
    }
    xva = *(const f32x4*)xp0;
    xvb = *(const f32x4*)xp1;
    xp0 += st0;
    xp1 += st1;
    pack_x(xva, xvb, xmask, xhi, xlo);  // fragments for step 0
  }

  __syncthreads();  // LDS zero-init visible

#pragma unroll 1
  for (int i = 0; i <= T_SEQ; ++i) {
    const int par = i & 1;
    if (!isB) {
      if (i < T_SEQ) {
        // ==== layer 0, time i: gates = b + Wx.x(i) + Wh.h0(i-1) ====
        const unsigned* r0 = hpf + (par ^ 1) * 1024 + n16 * 32;  // layer0
        v4i hh0 = *(const v4i*)(r0 + b0w);
        v4i hl0 = *(const v4i*)(r0 + 512 + b0w);
        v4i hh1 = *(const v4i*)(r0 + b1w);
        v4i hl1 = *(const v4i*)(r0 + 512 + b1w);
        const bool pf = i < T_SEQ - 1;
        if (pf) {  // prefetch x(i+1); stays in flight across BAR()
          xva = *(const f32x4*)xp0;
          xvb = *(const f32x4*)xp1;
          xp0 += st0;
          xp1 += st1;
        }
        f32x4 acc[4];
#pragma unroll
        for (int g = 0; g < 4; ++g) acc[g] = biasf[g];
        // T5: high priority through the MFMA block (partner wave is in its
        // pointwise tail and doesn't need the issue slots).
        __builtin_amdgcn_s_setprio(1);
        // Round-robin over the 4 acc chains. x products first (no LDS dep).
#pragma unroll
        for (int g = 0; g < 4; ++g) MFMA(acc[g], WA_X(g, 0), xhi);
#pragma unroll
        for (int g = 0; g < 4; ++g) MFMA(acc[g], WA_X(g, 0), xlo);
#pragma unroll
        for (int g = 0; g < 4; ++g) MFMA(acc[g], WA_X(g, 1), xhi);
#pragma unroll
        for (int g = 0; g < 4; ++g) MFMA(acc[g], WA_H(g, 0, 0), hh0);
#pragma unroll
        for (int g = 0; g < 4; ++g) MFMA(acc[g], WA_H(g, 0, 0), hl0);
#pragma unroll
        for (int g = 0; g < 4; ++g) MFMA(acc[g], WA_H(g, 0, 1), hh0);
#pragma unroll
        for (int g = 0; g < 4; ++g) MFMA(acc[g], WA_H(g, 1, 0), hh1);
#pragma unroll
        for (int g = 0; g < 4; ++g) MFMA(acc[g], WA_H(g, 1, 0), hl1);
#pragma unroll
        for (int g = 0; g < 4; ++g) MFMA(acc[g], WA_H(g, 1, 1), hh1);
        __builtin_amdgcn_s_setprio(0);
        unsigned hpk, lpk;
        pointwise(acc, grp, ca, cb, hpk, lpk);
        hpf[wroff + par * 1024] = hpk;
        hpf[wroff + par * 1024 + 512] = lpk;
        if (pf) pack_x(xva, xvb, xmask, xhi, xlo);  // fragments for step i+1
      }
    } else {
      if (i >= 1) {
        // ==== layer 1, time i-1: gates = b + Wy.h0(i-1) + Wh.h1(i-2) ====
        const unsigned* r0 = hpf + (par ^ 1) * 1024 + n16 * 32;         // layer0 (y)
        const unsigned* r1 = hpf + 2048 + (par ^ 1) * 1024 + n16 * 32;  // layer1 (h)
        v4i yh0 = *(const v4i*)(r0 + b0w);
        v4i yl0 = *(const v4i*)(r0 + 512 + b0w);
        v4i yh1 = *(const v4i*)(r0 + b1w);
        v4i yl1 = *(const v4i*)(r0 + 512 + b1w);
        v4i hh0 = *(const v4i*)(r1 + b0w);
        v4i hl0 = *(const v4i*)(r1 + 512 + b0w);
        v4i hh1 = *(const v4i*)(r1 + b1w);
        v4i hl1 = *(const v4i*)(r1 + 512 + b1w);
        f32x4 acc[4];
#pragma unroll
        for (int g = 0; g < 4; ++g) acc[g] = biasf[g];
        __builtin_amdgcn_s_setprio(1);
        // Round-robin over the 4 acc chains (dep distance 4).
#pragma unroll
        for (int g = 0; g < 4; ++g) MFMA(acc[g], WB_Y(g, 0, 0), yh0);
#pragma unroll
        for (int g = 0; g < 4; ++g) MFMA(acc[g], WB_Y(g, 0, 0), yl0);
#pragma unroll
        for (int g = 0; g < 4; ++g) MFMA(acc[g], WB_Y(g, 0, 1), yh0);
#pragma unroll
        for (int g = 0; g < 4; ++g) MFMA(acc[g], WB_H(g, 0, 0), hh0);
#pragma unroll
        for (int g = 0; g < 4; ++g) MFMA(acc[g], WB_H(g, 0, 0), hl0);
#pragma unroll
        for (int g = 0; g < 4; ++g) MFMA(acc[g], WB_H(g, 0, 1), hh0);
#pragma unroll
        for (int g = 0; g < 4; ++g) MFMA(acc[g], WB_Y(g, 1, 0), yh1);
#pragma unroll
        for (int g = 0; g < 4; ++g) MFMA(acc[g], WB_Y(g, 1, 0), yl1);
#pragma unroll
        for (int g = 0; g < 4; ++g) MFMA(acc[g], WB_Y(g, 1, 1), yh1);
#pragma unroll
        for (int g = 0; g < 4; ++g) MFMA(acc[g], WB_H(g, 1, 0), hh1);
#pragma unroll
        for (int g = 0; g < 4; ++g) MFMA(acc[g], WB_H(g, 1, 0), hl1);
#pragma unroll
        for (int g = 0; g < 4; ++g) MFMA(acc[g], WB_H(g, 1, 1), hh1);
        __builtin_amdgcn_s_setprio(0);
        unsigned hpk, lpk;
        pointwise(acc, grp, ca, cb, hpk, lpk);
        hpf[wroff + par * 1024] = hpk;
        hpf[wroff + par * 1024 + 512] = lpk;
      }
    }
    BAR();
  }

  // ---- projection: out[b] = h1(511) @ w_out^T + b_out; h1(511) at layer1/par0 ----
  if (tid < 8 * OUT_N) {
    const int b = tid / OUT_N, j = tid - b * OUT_N;
    float s = b_out[j];
    const unsigned* hrow = hpf + 2048 + b * 32;  // layer1, par0, hi; lo at +512
    const int swb = b << 2;                      // b < 8
    for (int p = 0; p < 32; ++p) {
      const int wsw = p ^ swb;
      const unsigned hw = hrow[wsw];
      const unsigned lw = hrow[wsw + 512];
      const float h0v = __uint_as_float(hw << 16) + __uint_as_float(lw << 16);
      const float h1v = __uint_as_float(hw & 0xffff0000u) + __uint_as_float(lw & 0xffff0000u);
      s = fmaf(w_out[j * HID + 2 * p], h0v, s);
      s = fmaf(w_out[j * HID + 2 * p + 1], h1v, s);
    }
    out[(blk * 8 + b) * OUT_N + j] = s;
  }
}

extern "C" void kernel_launch(void* const* d_in, const int* in_sizes, int n_in,
                              void* d_out, int out_size, void* d_ws, size_t ws_size,
                              hipStream_t stream) {
  const float* x = (const float*)d_in[0];
  const float* w_ih0 = (const float*)d_in[1];
  const float* w_hh0 = (const float*)d_in[2];
  const float* b_ih0 = (const float*)d_in[3];
  const float* b_hh0 = (const float*)d_in[4];
  const float* w_ih1 = (const float*)d_in[5];
  const float* w_hh1 = (const float*)d_in[6];
  const float* b_ih1 = (const float*)d_in[7];
  const float* b_hh1 = (const float*)d_in[8];
  const float* w_out = (const float*)d_in[9];
  const float* b_out = (const float*)d_in[10];
  float* out = (float*)d_out;

  hipLaunchKernelGGL(lstm_pipe, dim3(2048 / 8), dim3(512), 0, stream,
                     x, w_ih0, w_hh0, b_ih0, b_hh0,
                     w_ih1, w_hh1, b_ih1, b_hh1, w_out, b_out, out);
}